// Round 10
// baseline (40.779 us; speedup 1.0000x reference)
//
#include <hip/hip_runtime.h>
#include <math.h>

#define NPTS 4096
#define NB 8
#define NTOT (2*NB*NPTS)    // 65536 points (both sets)
#define NQTOT NTOT
#define EPSF 1e-12f
#define NCHUNK 16
#define CCH 256             // candidates per chunk
#define QPT 4               // queries per thread; 1024 blocks -> 4 waves/SIMD

static __device__ __forceinline__ float fmin3(float a, float b, float c){
    float d;
    asm("v_min3_f32 %0, %1, %2, %3" : "=v"(d) : "v"(a), "v"(b), "v"(c));
    return d;
}

static __device__ __forceinline__ void project_pt(const float* __restrict__ p3,
                                                  const float* __restrict__ Pb,
                                                  float& ix, float& iy){
    float x = p3[0], y = p3[1], z = p3[2];
    float px = fmaf(Pb[0],x, fmaf(Pb[1],y, fmaf(Pb[2],z,  Pb[3])));
    float py = fmaf(Pb[4],x, fmaf(Pb[5],y, fmaf(Pb[6],z,  Pb[7])));
    float pz = fmaf(Pb[8],x, fmaf(Pb[9],y, fmaf(Pb[10],z, Pb[11])));
    ix = px / pz;
    iy = py / pz;
}

// Project all 65536 points once: proj[i] = {x, y, x^2+y^2, 0}.
// gt occupies [0,32768), pred [32768,65536) — matches query/candidate indexing.
__global__ __launch_bounds__(256) void project_all(
        const float* __restrict__ pred, const float* __restrict__ gt,
        const float* __restrict__ P, float4* __restrict__ proj){
    int i = blockIdx.x * 256 + threadIdx.x;
    int set = i >> 15;
    int b   = (i >> 12) & 7;
    const float* src = set ? pred : gt;
    const float* p3  = src + (size_t)(i & 32767) * 3;
    const float* Pb  = P + b * 12;
    float ix, iy; project_pt(p3, Pb, ix, iy);
    proj[i] = make_float4(ix, iy, fmaf(ix,ix, iy*iy), 0.0f);
}

// 1024 blocks = 2 dirs x 8 batches x 4 query-groups x 16 chunks.
// NO LDS, NO barrier: candidates are read at a wave-uniform address from
// proj[] -> AMDGPU uniformity analysis emits s_load through the scalar
// cache (separate pipe from LDS/VMEM). Queries: coalesced b128 loads.
__global__ __launch_bounds__(256) void chamfer_smem(
        const float4* __restrict__ proj, float* __restrict__ minpart){
    int bid   = blockIdx.x;
    int chunk = bid & 15;
    int qg    = (bid >> 4) & 3;
    int b     = (bid >> 6) & 7;
    int dir   = (bid >> 9) & 1;
    int t = threadIdx.x;

    int qbase = dir*(NB*NPTS) + b*NPTS + qg*1024;          // this block's queries
    int cbase = (1-dir)*(NB*NPTS) + b*NPTS + chunk*CCH;    // uniform candidates

    float m2ax[QPT], m2ay[QPT], a2[QPT], mn[QPT];
    #pragma unroll
    for (int q = 0; q < QPT; ++q){
        float4 a = proj[qbase + q*256 + t];
        m2ax[q] = -2.0f * a.x;
        m2ay[q] = -2.0f * a.y;
        a2[q]   = a.z;
        mn[q]   = 3.4e38f;
    }

    const float4* __restrict__ cp = proj + cbase;
    #pragma unroll 4
    for (int ci = 0; ci < CCH; ci += 2){
        float4 c0 = cp[ci];        // wave-uniform -> s_load (scalar cache)
        float4 c1 = cp[ci+1];
        #pragma unroll
        for (int q = 0; q < QPT; ++q){
            float t0 = fmaf(m2ay[q], c0.y, fmaf(m2ax[q], c0.x, c0.z));
            float t1 = fmaf(m2ay[q], c1.y, fmaf(m2ax[q], c1.x, c1.z));
            mn[q] = fmin3(t0, t1, mn[q]);
        }
    }

    int gq = qbase + t;
    #pragma unroll
    for (int q = 0; q < QPT; ++q){
        minpart[(size_t)chunk*NQTOT + gq + q*256] = mn[q] + a2[q];
    }
}

// 16-way min across chunks, sqrt, per-block partial sum.  (R9-proven, unchanged)
__global__ __launch_bounds__(256) void reduce_min_sum(
        const float* __restrict__ minpart, float* __restrict__ partials){
    __shared__ float sm[256];
    int t = threadIdx.x;
    int i = blockIdx.x * 256 + t;   // 256 blocks cover 65536 queries
    float m0 = minpart[i];
    #pragma unroll
    for (int c = 1; c < NCHUNK; ++c) m0 = fminf(m0, minpart[(size_t)c*NQTOT + i]);
    float s = sqrtf(fmaxf(m0, EPSF));
    sm[t] = s; __syncthreads();
    #pragma unroll
    for (int o = 128; o > 0; o >>= 1){
        if (t < o) sm[t] += sm[t + o];
        __syncthreads();
    }
    if (t == 0) partials[blockIdx.x] = sm[0];
}

__global__ void reduce_final(const float* __restrict__ partials,
                             float* __restrict__ out){
    __shared__ float sm[256];
    int t = threadIdx.x;
    sm[t] = partials[t];
    __syncthreads();
    #pragma unroll
    for (int o = 128; o > 0; o >>= 1){
        if (t < o) sm[t] += sm[t + o];
        __syncthreads();
    }
    if (t == 0) out[0] = sm[0] * (1.0f / 32768.0f);
}

extern "C" void kernel_launch(void* const* d_in, const int* in_sizes, int n_in,
                              void* d_out, int out_size, void* d_ws, size_t ws_size,
                              hipStream_t stream) {
    const float* pred = (const float*)d_in[0];
    const float* gt   = (const float*)d_in[1];
    const float* P    = (const float*)d_in[2];
    float* out = (float*)d_out;

    const size_t MINPART_BYTES = (size_t)NCHUNK * NQTOT * 4;   // 4 MB
    float*  minpart  = (float*)d_ws;
    float4* proj     = (float4*)((char*)d_ws + MINPART_BYTES);             // 1 MB
    float*  partials = (float*)((char*)d_ws + MINPART_BYTES + (size_t)NTOT*16);

    project_all<<<NTOT/256, 256, 0, stream>>>(pred, gt, P, proj);
    chamfer_smem<<<1024, 256, 0, stream>>>(proj, minpart);
    reduce_min_sum<<<256, 256, 0, stream>>>(minpart, partials);
    reduce_final<<<1, 256, 0, stream>>>(partials, out);
}